// Round 1
// baseline (6352.527 us; speedup 1.0000x reference)
//
#include <hip/hip_runtime.h>
#include <math.h>

#define D 128

// ---------------- zero workspace buffer ----------------
__global__ void zero_kernel(float4* __restrict__ buf, long n4) {
    long i = (long)blockIdx.x * blockDim.x + threadIdx.x;
    long stride = (long)gridDim.x * blockDim.x;
    for (; i < n4; i += stride) buf[i] = make_float4(0.f, 0.f, 0.f, 0.f);
}

// ---------------- h0 = emb_table[cncpt_ids] ----------------
__global__ void gather_kernel(const float* __restrict__ emb,
                              const int* __restrict__ ids,
                              float* __restrict__ h, int n_nodes) {
    int idx = blockIdx.x * blockDim.x + threadIdx.x;  // one float4 per thread
    int total = n_nodes * (D / 4);
    if (idx >= total) return;
    int node = idx >> 5;       // D/4 = 32 float4 per row
    int c = idx & 31;
    size_t cid = (size_t)ids[node];
    const float4* s = (const float4*)(emb + cid * D);
    float4* d = (float4*)(h + (size_t)node * D);
    d[c] = s[c];
}

// ---------------- agg[dst] += h[src] (edge-parallel atomics) ----------------
__global__ void scatter_kernel(const float* __restrict__ h,
                               const int* __restrict__ src,
                               const int* __restrict__ dst,
                               float* __restrict__ agg, int n_edges) {
    int idx = blockIdx.x * blockDim.x + threadIdx.x;  // 32 threads per edge
    int total = n_edges * (D / 4);
    if (idx >= total) return;
    int e = idx >> 5;
    int c = idx & 31;
    int s = src[e];
    int t = dst[e];
    float4 v = ((const float4*)(h + (size_t)s * D))[c];
    float* o = agg + (size_t)t * D + (size_t)c * 4;
    atomicAdd(o + 0, v.x);
    atomicAdd(o + 1, v.y);
    atomicAdd(o + 2, v.z);
    atomicAdd(o + 3, v.w);
}

// ---------------- y = relu(x @ W^T + b) ----------------
// Each block (64 threads) owns 64 output dims (half = blockIdx&1) and
// grid-strides over nodes. W^T half staged in LDS: Wt[k*64+dd] = W[(base+dd)*D+k]
// -> inner-loop read bank = dd%32, 2 lanes/bank = conflict-free on CDNA4.
__global__ __launch_bounds__(64) void linear_relu_kernel(
        const float* __restrict__ x, const float* __restrict__ W,
        const float* __restrict__ b, float* __restrict__ y, int n_nodes) {
    __shared__ float Wt[D * 64];   // 32 KiB
    __shared__ float xs[D];
    const int tid = threadIdx.x;           // 0..63
    const int half = blockIdx.x & 1;
    const int base = half * 64;

    // Stage W^T: i = k*64+dd -> conflict-free LDS writes; global reads are
    // 512B-strided but L1/L2-hot (W is 64 KiB total).
    for (int i = tid; i < D * 64; i += 64) {
        int k = i >> 6;
        int dd = i & 63;
        Wt[i] = W[(size_t)(base + dd) * D + k];
    }
    float bd = b[base + tid];
    __syncthreads();

    const int nblocks = gridDim.x >> 1;
    for (int node = blockIdx.x >> 1; node < n_nodes; node += nblocks) {
        const float* xr = x + (size_t)node * D;
        xs[tid] = xr[tid];
        xs[tid + 64] = xr[tid + 64];
        __syncthreads();
        float a0 = 0.f, a1 = 0.f, a2 = 0.f, a3 = 0.f;
        #pragma unroll
        for (int k = 0; k < D; k += 4) {
            a0 += xs[k + 0] * Wt[(k + 0) * 64 + tid];
            a1 += xs[k + 1] * Wt[(k + 1) * 64 + tid];
            a2 += xs[k + 2] * Wt[(k + 2) * 64 + tid];
            a3 += xs[k + 3] * Wt[(k + 3) * 64 + tid];
        }
        float acc = bd + ((a0 + a1) + (a2 + a3));
        y[(size_t)node * D + base + tid] = fmaxf(acc, 0.0f);
        __syncthreads();
    }
}

// ---------------- out[v] = sigmoid(dot(h[v], wout) + bout) ----------------
__global__ __launch_bounds__(256) void out_kernel(
        const float* __restrict__ h, const float* __restrict__ wout,
        const float* __restrict__ bout, float* __restrict__ out, int n_nodes) {
    int node = blockIdx.x * 4 + (threadIdx.x >> 6);
    int lane = threadIdx.x & 63;
    if (node >= n_nodes) return;
    const float* row = h + (size_t)node * D;
    float s = row[lane] * wout[lane] + row[lane + 64] * wout[lane + 64];
    #pragma unroll
    for (int off = 32; off > 0; off >>= 1)
        s += __shfl_down(s, off, 64);
    if (lane == 0)
        out[node] = 1.0f / (1.0f + expf(-(s + bout[0])));
}

extern "C" void kernel_launch(void* const* d_in, const int* in_sizes, int n_in,
                              void* d_out, int out_size, void* d_ws, size_t ws_size,
                              hipStream_t stream) {
    const int*   cncpt_ids = (const int*)d_in[0];
    const int*   src       = (const int*)d_in[1];
    const int*   dst       = (const int*)d_in[2];
    const float* emb       = (const float*)d_in[3];
    const float* W1        = (const float*)d_in[4];
    const float* b1        = (const float*)d_in[5];
    const float* W2        = (const float*)d_in[6];
    const float* b2        = (const float*)d_in[7];
    const float* Wout      = (const float*)d_in[8];
    const float* bout      = (const float*)d_in[9];
    float* out = (float*)d_out;

    const int n_nodes = in_sizes[0];
    const int n_edges = in_sizes[1];

    float* bufA = (float*)d_ws;                       // h buffers, N*D f32 each
    float* bufB = bufA + (size_t)n_nodes * D;

    const long n4 = (long)n_nodes * (D / 4);
    const int gather_grid  = (n_nodes * (D / 4) + 255) / 256;
    const int scatter_grid = (int)(((long)n_edges * (D / 4) + 255) / 256);

    // h0 = emb[ids] -> bufA
    gather_kernel<<<gather_grid, 256, 0, stream>>>(emb, cncpt_ids, bufA, n_nodes);

    // layer 1: agg = scatter(h0) -> bufB ; h1 = relu(agg@W1^T+b1) -> bufA
    zero_kernel<<<1024, 256, 0, stream>>>((float4*)bufB, n4);
    scatter_kernel<<<scatter_grid, 256, 0, stream>>>(bufA, src, dst, bufB, n_edges);
    linear_relu_kernel<<<4096, 64, 0, stream>>>(bufB, W1, b1, bufA, n_nodes);

    // layer 2: agg = scatter(h1) -> bufB ; h2 = relu(agg@W2^T+b2) -> bufA
    zero_kernel<<<1024, 256, 0, stream>>>((float4*)bufB, n4);
    scatter_kernel<<<scatter_grid, 256, 0, stream>>>(bufA, src, dst, bufB, n_edges);
    linear_relu_kernel<<<4096, 64, 0, stream>>>(bufB, W2, b2, bufA, n_nodes);

    // out = sigmoid(h2 @ Wout^T + bout)
    out_kernel<<<(n_nodes + 3) / 4, 256, 0, stream>>>(bufA, Wout, bout, out, n_nodes);
}

// Round 2
// 1398.926 us; speedup vs baseline: 4.5410x; 4.5410x over previous
//
#include <hip/hip_runtime.h>
#include <math.h>

#define D 128
#define SCAN_B 256   // elements per scan block

// ---------------- zero int buffer ----------------
__global__ void zero_int_kernel(int* __restrict__ buf, int n) {
    int i = blockIdx.x * blockDim.x + threadIdx.x;
    if (i < n) buf[i] = 0;
}

// ---------------- h0 = emb_table[cncpt_ids] ----------------
__global__ void gather_kernel(const float* __restrict__ emb,
                              const int* __restrict__ ids,
                              float* __restrict__ h, int n_nodes) {
    int idx = blockIdx.x * blockDim.x + threadIdx.x;  // one float4 per thread
    int total = n_nodes * (D / 4);
    if (idx >= total) return;
    int node = idx >> 5;       // D/4 = 32 float4 per row
    int c = idx & 31;
    size_t cid = (size_t)ids[node];
    const float4* s = (const float4*)(emb + cid * D);
    float4* d = (float4*)(h + (size_t)node * D);
    d[c] = s[c];
}

// ---------------- CSR build: degree histogram ----------------
__global__ void degree_kernel(const int* __restrict__ dst,
                              int* __restrict__ deg, int n_edges) {
    int e = blockIdx.x * blockDim.x + threadIdx.x;
    if (e < n_edges) atomicAdd(&deg[dst[e]], 1);
}

// ---------------- CSR build: block-level exclusive scan ----------------
// row_ptr[i] = exclusive scan of deg within block; blocksums[b] = block total
__global__ __launch_bounds__(SCAN_B) void scan_block_kernel(
        const int* __restrict__ deg, int* __restrict__ row_ptr,
        int* __restrict__ blocksums, int n) {
    __shared__ int s[SCAN_B];
    int i = blockIdx.x * SCAN_B + threadIdx.x;
    int v = (i < n) ? deg[i] : 0;
    s[threadIdx.x] = v;
    __syncthreads();
    #pragma unroll
    for (int off = 1; off < SCAN_B; off <<= 1) {
        int t = (threadIdx.x >= off) ? s[threadIdx.x - off] : 0;
        __syncthreads();
        s[threadIdx.x] += t;
        __syncthreads();
    }
    if (i < n) row_ptr[i] = s[threadIdx.x] - v;      // exclusive
    if (threadIdx.x == SCAN_B - 1) blocksums[blockIdx.x] = s[SCAN_B - 1];
}

// ---------------- CSR build: scan the block sums (single block) ----------------
__global__ __launch_bounds__(512) void scan_sums_kernel(int* __restrict__ blocksums,
                                                        int nb) {
    __shared__ int s[512];
    int v = (threadIdx.x < nb) ? blocksums[threadIdx.x] : 0;
    s[threadIdx.x] = v;
    __syncthreads();
    #pragma unroll
    for (int off = 1; off < 512; off <<= 1) {
        int t = (threadIdx.x >= off) ? s[threadIdx.x - off] : 0;
        __syncthreads();
        s[threadIdx.x] += t;
        __syncthreads();
    }
    if (threadIdx.x < nb) blocksums[threadIdx.x] = s[threadIdx.x] - v;  // exclusive
}

// ---------------- CSR build: add block offsets + init cursor ----------------
__global__ void add_offsets_kernel(int* __restrict__ row_ptr,
                                   const int* __restrict__ blocksums,
                                   int* __restrict__ cursor, int n, int n_nodes) {
    int i = blockIdx.x * blockDim.x + threadIdx.x;
    if (i >= n) return;
    int rp = row_ptr[i] + blocksums[i / SCAN_B];
    row_ptr[i] = rp;
    if (i < n_nodes) cursor[i] = rp;
}

// ---------------- CSR build: fill edge lists ----------------
__global__ void csr_fill_kernel(const int* __restrict__ src,
                                const int* __restrict__ dst,
                                int* __restrict__ cursor,
                                int* __restrict__ esrc, int n_edges) {
    int e = blockIdx.x * blockDim.x + threadIdx.x;
    if (e >= n_edges) return;
    int pos = atomicAdd(&cursor[dst[e]], 1);
    esrc[pos] = src[e];
}

// ---------------- agg[v] = sum_{e: dst=v} h[src[e]] ----------------
// One 64-lane wave per node; each lane owns a float2 slice of the 128-dim row.
__global__ __launch_bounds__(256) void agg_kernel(
        const float2* __restrict__ h, const int* __restrict__ row_ptr,
        const int* __restrict__ esrc, float2* __restrict__ agg, int n_nodes) {
    int node = blockIdx.x * 4 + (threadIdx.x >> 6);
    int lane = threadIdx.x & 63;
    if (node >= n_nodes) return;
    int beg = row_ptr[node], end = row_ptr[node + 1];
    float ax = 0.f, ay = 0.f;
    int i = beg;
    for (; i + 1 < end; i += 2) {
        int s0 = esrc[i], s1 = esrc[i + 1];
        float2 v0 = h[(size_t)s0 * 64 + lane];
        float2 v1 = h[(size_t)s1 * 64 + lane];
        ax += v0.x + v1.x;
        ay += v0.y + v1.y;
    }
    if (i < end) {
        float2 v = h[(size_t)esrc[i] * 64 + lane];
        ax += v.x; ay += v.y;
    }
    float2 r; r.x = ax; r.y = ay;
    agg[(size_t)node * 64 + lane] = r;
}

// ---------------- y = relu(x @ W^T + b) ----------------
__global__ __launch_bounds__(64) void linear_relu_kernel(
        const float* __restrict__ x, const float* __restrict__ W,
        const float* __restrict__ b, float* __restrict__ y, int n_nodes) {
    __shared__ float Wt[D * 64];   // 32 KiB
    __shared__ float xs[D];
    const int tid = threadIdx.x;           // 0..63
    const int half = blockIdx.x & 1;
    const int base = half * 64;

    for (int i = tid; i < D * 64; i += 64) {
        int k = i >> 6;
        int dd = i & 63;
        Wt[i] = W[(size_t)(base + dd) * D + k];
    }
    float bd = b[base + tid];
    __syncthreads();

    const int nblocks = gridDim.x >> 1;
    for (int node = blockIdx.x >> 1; node < n_nodes; node += nblocks) {
        const float* xr = x + (size_t)node * D;
        xs[tid] = xr[tid];
        xs[tid + 64] = xr[tid + 64];
        __syncthreads();
        float a0 = 0.f, a1 = 0.f, a2 = 0.f, a3 = 0.f;
        #pragma unroll
        for (int k = 0; k < D; k += 4) {
            a0 += xs[k + 0] * Wt[(k + 0) * 64 + tid];
            a1 += xs[k + 1] * Wt[(k + 1) * 64 + tid];
            a2 += xs[k + 2] * Wt[(k + 2) * 64 + tid];
            a3 += xs[k + 3] * Wt[(k + 3) * 64 + tid];
        }
        float acc = bd + ((a0 + a1) + (a2 + a3));
        y[(size_t)node * D + base + tid] = fmaxf(acc, 0.0f);
        __syncthreads();
    }
}

// ---------------- out[v] = sigmoid(dot(h[v], wout) + bout) ----------------
__global__ __launch_bounds__(256) void out_kernel(
        const float* __restrict__ h, const float* __restrict__ wout,
        const float* __restrict__ bout, float* __restrict__ out, int n_nodes) {
    int node = blockIdx.x * 4 + (threadIdx.x >> 6);
    int lane = threadIdx.x & 63;
    if (node >= n_nodes) return;
    const float* row = h + (size_t)node * D;
    float s = row[lane] * wout[lane] + row[lane + 64] * wout[lane + 64];
    #pragma unroll
    for (int off = 32; off > 0; off >>= 1)
        s += __shfl_down(s, off, 64);
    if (lane == 0)
        out[node] = 1.0f / (1.0f + expf(-(s + bout[0])));
}

extern "C" void kernel_launch(void* const* d_in, const int* in_sizes, int n_in,
                              void* d_out, int out_size, void* d_ws, size_t ws_size,
                              hipStream_t stream) {
    const int*   cncpt_ids = (const int*)d_in[0];
    const int*   src       = (const int*)d_in[1];
    const int*   dst       = (const int*)d_in[2];
    const float* emb       = (const float*)d_in[3];
    const float* W1        = (const float*)d_in[4];
    const float* b1        = (const float*)d_in[5];
    const float* W2        = (const float*)d_in[6];
    const float* b2        = (const float*)d_in[7];
    const float* Wout      = (const float*)d_in[8];
    const float* bout      = (const float*)d_in[9];
    float* out = (float*)d_out;

    const int n_nodes = in_sizes[0];
    const int n_edges = in_sizes[1];

    // ---- workspace carve-up ----
    float* bufA = (float*)d_ws;                       // N*D f32
    float* bufB = bufA + (size_t)n_nodes * D;         // N*D f32
    int*   deg      = (int*)(bufB + (size_t)n_nodes * D); // N+1 ints
    int*   row_ptr  = deg + (n_nodes + 1);            // N+1 ints
    int*   cursor   = row_ptr + (n_nodes + 1);        // N ints
    int*   blocksums= cursor + n_nodes;               // 512 ints
    int*   esrc     = blocksums + 512;                // E ints

    const int np1 = n_nodes + 1;
    const int nb_scan = (np1 + SCAN_B - 1) / SCAN_B;  // <= 512

    // ---- h0 = emb[ids] -> bufA ----
    gather_kernel<<<(n_nodes * (D / 4) + 255) / 256, 256, 0, stream>>>(
        emb, cncpt_ids, bufA, n_nodes);

    // ---- CSR build (per call; ws is re-poisoned) ----
    zero_int_kernel<<<(np1 + 255) / 256, 256, 0, stream>>>(deg, np1);
    degree_kernel<<<(n_edges + 255) / 256, 256, 0, stream>>>(dst, deg, n_edges);
    scan_block_kernel<<<nb_scan, SCAN_B, 0, stream>>>(deg, row_ptr, blocksums, np1);
    scan_sums_kernel<<<1, 512, 0, stream>>>(blocksums, nb_scan);
    add_offsets_kernel<<<(np1 + 255) / 256, 256, 0, stream>>>(
        row_ptr, blocksums, cursor, np1, n_nodes);
    csr_fill_kernel<<<(n_edges + 255) / 256, 256, 0, stream>>>(
        src, dst, cursor, esrc, n_edges);

    const int agg_grid = (n_nodes + 3) / 4;

    // ---- layer 1 ----
    agg_kernel<<<agg_grid, 256, 0, stream>>>(
        (const float2*)bufA, row_ptr, esrc, (float2*)bufB, n_nodes);
    linear_relu_kernel<<<4096, 64, 0, stream>>>(bufB, W1, b1, bufA, n_nodes);

    // ---- layer 2 ----
    agg_kernel<<<agg_grid, 256, 0, stream>>>(
        (const float2*)bufA, row_ptr, esrc, (float2*)bufB, n_nodes);
    linear_relu_kernel<<<4096, 64, 0, stream>>>(bufB, W2, b2, bufA, n_nodes);

    // ---- output ----
    out_kernel<<<(n_nodes + 3) / 4, 256, 0, stream>>>(bufA, Wout, bout, out, n_nodes);
}

// Round 3
// 870.279 us; speedup vs baseline: 7.2994x; 1.6074x over previous
//
#include <hip/hip_runtime.h>
#include <math.h>

#define D 128
#define SCAN_B 256   // elements per scan block

typedef __attribute__((ext_vector_type(8))) short bfrag;   // 8 bf16 (4 VGPRs)
typedef __attribute__((ext_vector_type(4))) float ffrag;   // 4 fp32 acc

__device__ inline unsigned short f2bf(float f) {           // RNE fp32->bf16
    unsigned u = __float_as_uint(f);
    u += 0x7FFF + ((u >> 16) & 1);
    return (unsigned short)(u >> 16);
}
__device__ inline float bf2f(unsigned short h) {
    return __uint_as_float(((unsigned)h) << 16);
}

// ---------------- zero int buffer ----------------
__global__ void zero_int_kernel(int* __restrict__ buf, int n) {
    int i = blockIdx.x * blockDim.x + threadIdx.x;
    if (i < n) buf[i] = 0;
}

// ---------------- split W (fp32) -> Whi + Wlo (bf16) ----------------
__global__ void wsplit_kernel(const float* __restrict__ W,
                              unsigned short* __restrict__ hi,
                              unsigned short* __restrict__ lo, int n) {
    int i = blockIdx.x * blockDim.x + threadIdx.x;
    if (i >= n) return;
    float f = W[i];
    unsigned short h = f2bf(f);
    hi[i] = h;
    lo[i] = f2bf(f - bf2f(h));
}

// ---------------- h0 = emb_table[cncpt_ids] ----------------
__global__ void gather_kernel(const float* __restrict__ emb,
                              const int* __restrict__ ids,
                              float* __restrict__ h, int n_nodes) {
    int idx = blockIdx.x * blockDim.x + threadIdx.x;  // one float4 per thread
    int total = n_nodes * (D / 4);
    if (idx >= total) return;
    int node = idx >> 5;       // D/4 = 32 float4 per row
    int c = idx & 31;
    size_t cid = (size_t)ids[node];
    const float4* s = (const float4*)(emb + cid * D);
    float4* d = (float4*)(h + (size_t)node * D);
    d[c] = s[c];
}

// ---------------- CSR build ----------------
__global__ void degree_kernel(const int* __restrict__ dst,
                              int* __restrict__ deg, int n_edges) {
    int e = blockIdx.x * blockDim.x + threadIdx.x;
    if (e < n_edges) atomicAdd(&deg[dst[e]], 1);
}

__global__ __launch_bounds__(SCAN_B) void scan_block_kernel(
        const int* __restrict__ deg, int* __restrict__ row_ptr,
        int* __restrict__ blocksums, int n) {
    __shared__ int s[SCAN_B];
    int i = blockIdx.x * SCAN_B + threadIdx.x;
    int v = (i < n) ? deg[i] : 0;
    s[threadIdx.x] = v;
    __syncthreads();
    #pragma unroll
    for (int off = 1; off < SCAN_B; off <<= 1) {
        int t = (threadIdx.x >= off) ? s[threadIdx.x - off] : 0;
        __syncthreads();
        s[threadIdx.x] += t;
        __syncthreads();
    }
    if (i < n) row_ptr[i] = s[threadIdx.x] - v;      // exclusive
    if (threadIdx.x == SCAN_B - 1) blocksums[blockIdx.x] = s[SCAN_B - 1];
}

__global__ __launch_bounds__(512) void scan_sums_kernel(int* __restrict__ blocksums,
                                                        int nb) {
    __shared__ int s[512];
    int v = (threadIdx.x < nb) ? blocksums[threadIdx.x] : 0;
    s[threadIdx.x] = v;
    __syncthreads();
    #pragma unroll
    for (int off = 1; off < 512; off <<= 1) {
        int t = (threadIdx.x >= off) ? s[threadIdx.x - off] : 0;
        __syncthreads();
        s[threadIdx.x] += t;
        __syncthreads();
    }
    if (threadIdx.x < nb) blocksums[threadIdx.x] = s[threadIdx.x] - v;  // exclusive
}

__global__ void add_offsets_kernel(int* __restrict__ row_ptr,
                                   const int* __restrict__ blocksums,
                                   int* __restrict__ cursor, int n, int n_nodes) {
    int i = blockIdx.x * blockDim.x + threadIdx.x;
    if (i >= n) return;
    int rp = row_ptr[i] + blocksums[i / SCAN_B];
    row_ptr[i] = rp;
    if (i < n_nodes) cursor[i] = rp;
}

__global__ void csr_fill_kernel(const int* __restrict__ src,
                                const int* __restrict__ dst,
                                int* __restrict__ cursor,
                                int* __restrict__ esrc, int n_edges) {
    int e = blockIdx.x * blockDim.x + threadIdx.x;
    if (e >= n_edges) return;
    int pos = atomicAdd(&cursor[dst[e]], 1);
    esrc[pos] = src[e];
}

// ---------------- agg[v] = sum_{e: dst=v} h[src[e]] ----------------
__global__ __launch_bounds__(256) void agg_kernel(
        const float2* __restrict__ h, const int* __restrict__ row_ptr,
        const int* __restrict__ esrc, float2* __restrict__ agg, int n_nodes) {
    int node = blockIdx.x * 4 + (threadIdx.x >> 6);
    int lane = threadIdx.x & 63;
    if (node >= n_nodes) return;
    int beg = row_ptr[node], end = row_ptr[node + 1];
    float ax = 0.f, ay = 0.f;
    int i = beg;
    for (; i + 1 < end; i += 2) {
        int s0 = esrc[i], s1 = esrc[i + 1];
        float2 v0 = h[(size_t)s0 * 64 + lane];
        float2 v1 = h[(size_t)s1 * 64 + lane];
        ax += v0.x + v1.x;
        ay += v0.y + v1.y;
    }
    if (i < end) {
        float2 v = h[(size_t)esrc[i] * 64 + lane];
        ax += v.x; ay += v.y;
    }
    float2 r; r.x = ax; r.y = ay;
    agg[(size_t)node * 64 + lane] = r;
}

// ---------------- y = relu(x @ W^T + b) via bf16x3 MFMA ----------------
// One wave per 16-node group; computes all 128 output dims (8 nt-tiles of 16).
// A-frag: lane holds X[node = g*16 + (lane&15)][k = kt*32 + quad*8 .. +7],
// split into bf16 hi/lo in registers. B-frag: lane holds W[n][k..k+7] with
// n = nt*16 + (lane&15) — exactly the MFMA B layout, read straight from the
// pre-split row-major Whi/Wlo (64 KB, L1/L2-hot; no LDS, no transpose).
// acc = Ahi*Bhi + Alo*Bhi + Ahi*Blo (fp32 MFMA accumulate) ~ fp32 precision.
// fuse_out: apply relu+bias, dot with wout across the 8 nt tiles, quad-local
// shfl reduce, sigmoid, write logits (layer 2 + output head fused).
__global__ __launch_bounds__(256) void linear_mfma_kernel(
        const float* __restrict__ x,
        const unsigned short* __restrict__ Whi,
        const unsigned short* __restrict__ Wlo,
        const float* __restrict__ b,
        float* __restrict__ y,
        const float* __restrict__ wout,
        const float* __restrict__ bout,
        float* __restrict__ outp,
        int n_nodes, int fuse_out) {
    const int lane = threadIdx.x & 63;
    const int col  = lane & 15;        // m (A) / n (B) index
    const int quad = lane >> 4;        // k-chunk selector
    const int wave = blockIdx.x * 4 + (threadIdx.x >> 6);
    const int nwaves = gridDim.x * 4;
    const int ngroups = (n_nodes + 15) >> 4;

    // per-lane bias / wout values for each nt tile
    float bvals[8], wvals[8];
    #pragma unroll
    for (int nt = 0; nt < 8; ++nt) {
        bvals[nt] = b[nt * 16 + col];
        wvals[nt] = fuse_out ? wout[nt * 16 + col] : 0.f;
    }
    const float bout0 = fuse_out ? bout[0] : 0.f;

    for (int g = wave; g < ngroups; g += nwaves) {
        int node = g * 16 + col;
        int nload = node < n_nodes ? node : (n_nodes - 1);

        // ---- load + split A fragments (4 kt chunks of 8 floats) ----
        bfrag ahi[4], alo[4];
        #pragma unroll
        for (int kt = 0; kt < 4; ++kt) {
            const float4* xp = (const float4*)(x + (size_t)nload * D + kt * 32 + quad * 8);
            float4 v0 = xp[0];
            float4 v1 = xp[1];
            float vv[8] = {v0.x, v0.y, v0.z, v0.w, v1.x, v1.y, v1.z, v1.w};
            #pragma unroll
            for (int j = 0; j < 8; ++j) {
                unsigned short h = f2bf(vv[j]);
                ahi[kt][j] = (short)h;
                alo[kt][j] = (short)f2bf(vv[j] - bf2f(h));
            }
        }

        const size_t bbase = (size_t)col * D + quad * 8;   // within-row offset
        float part0 = 0.f, part1 = 0.f, part2 = 0.f, part3 = 0.f;

        #pragma unroll
        for (int nt = 0; nt < 8; ++nt) {
            ffrag c = {0.f, 0.f, 0.f, 0.f};
            #pragma unroll
            for (int kt = 0; kt < 4; ++kt) {
                size_t off = (size_t)nt * 16 * D + bbase + kt * 32;
                bfrag bh = *(const bfrag*)(Whi + off);
                bfrag bl = *(const bfrag*)(Wlo + off);
                c = __builtin_amdgcn_mfma_f32_16x16x32_bf16(ahi[kt], bh, c, 0, 0, 0);
                c = __builtin_amdgcn_mfma_f32_16x16x32_bf16(alo[kt], bh, c, 0, 0, 0);
                c = __builtin_amdgcn_mfma_f32_16x16x32_bf16(ahi[kt], bl, c, 0, 0, 0);
            }
            // C layout: value r is C[row = quad*4 + r][col], row = node offset
            if (fuse_out) {
                float h0 = fmaxf(c[0] + bvals[nt], 0.f);
                float h1 = fmaxf(c[1] + bvals[nt], 0.f);
                float h2 = fmaxf(c[2] + bvals[nt], 0.f);
                float h3 = fmaxf(c[3] + bvals[nt], 0.f);
                part0 += h0 * wvals[nt];
                part1 += h1 * wvals[nt];
                part2 += h2 * wvals[nt];
                part3 += h3 * wvals[nt];
            } else {
                #pragma unroll
                for (int r = 0; r < 4; ++r) {
                    int onode = g * 16 + quad * 4 + r;
                    if (onode < n_nodes)
                        y[(size_t)onode * D + nt * 16 + col] = fmaxf(c[r] + bvals[nt], 0.f);
                }
            }
        }

        if (fuse_out) {
            float part[4] = {part0, part1, part2, part3};
            #pragma unroll
            for (int r = 0; r < 4; ++r) {
                float s = part[r];
                s += __shfl_xor(s, 1, 64);
                s += __shfl_xor(s, 2, 64);
                s += __shfl_xor(s, 4, 64);
                s += __shfl_xor(s, 8, 64);   // reduce over 16 cols within quad
                int onode = g * 16 + quad * 4 + r;
                if (col == 0 && onode < n_nodes)
                    outp[onode] = 1.0f / (1.0f + expf(-(s + bout0)));
            }
        }
    }
}

extern "C" void kernel_launch(void* const* d_in, const int* in_sizes, int n_in,
                              void* d_out, int out_size, void* d_ws, size_t ws_size,
                              hipStream_t stream) {
    const int*   cncpt_ids = (const int*)d_in[0];
    const int*   src       = (const int*)d_in[1];
    const int*   dst       = (const int*)d_in[2];
    const float* emb       = (const float*)d_in[3];
    const float* W1        = (const float*)d_in[4];
    const float* b1        = (const float*)d_in[5];
    const float* W2        = (const float*)d_in[6];
    const float* b2        = (const float*)d_in[7];
    const float* Wout      = (const float*)d_in[8];
    const float* bout      = (const float*)d_in[9];
    float* out = (float*)d_out;

    const int n_nodes = in_sizes[0];
    const int n_edges = in_sizes[1];

    // ---- workspace carve-up ----
    float* bufA = (float*)d_ws;                           // N*D f32
    float* bufB = bufA + (size_t)n_nodes * D;             // N*D f32
    int*   deg      = (int*)(bufB + (size_t)n_nodes * D); // N+1 ints
    int*   row_ptr  = deg + (n_nodes + 1);                // N+1 ints
    int*   cursor   = row_ptr + (n_nodes + 1);            // N ints
    int*   blocksums= cursor + n_nodes;                   // 512 ints
    int*   esrc     = blocksums + 512;                    // E ints
    unsigned short* W1hi = (unsigned short*)(esrc + n_edges);  // D*D each
    unsigned short* W1lo = W1hi + D * D;
    unsigned short* W2hi = W1lo + D * D;
    unsigned short* W2lo = W2hi + D * D;

    const int np1 = n_nodes + 1;
    const int nb_scan = (np1 + SCAN_B - 1) / SCAN_B;  // <= 512

    // ---- weight splits (bf16 hi/lo) ----
    wsplit_kernel<<<(D * D + 255) / 256, 256, 0, stream>>>(W1, W1hi, W1lo, D * D);
    wsplit_kernel<<<(D * D + 255) / 256, 256, 0, stream>>>(W2, W2hi, W2lo, D * D);

    // ---- h0 = emb[ids] -> bufA ----
    gather_kernel<<<(n_nodes * (D / 4) + 255) / 256, 256, 0, stream>>>(
        emb, cncpt_ids, bufA, n_nodes);

    // ---- CSR build (per call; ws is re-poisoned) ----
    zero_int_kernel<<<(np1 + 255) / 256, 256, 0, stream>>>(deg, np1);
    degree_kernel<<<(n_edges + 255) / 256, 256, 0, stream>>>(dst, deg, n_edges);
    scan_block_kernel<<<nb_scan, SCAN_B, 0, stream>>>(deg, row_ptr, blocksums, np1);
    scan_sums_kernel<<<1, 512, 0, stream>>>(blocksums, nb_scan);
    add_offsets_kernel<<<(np1 + 255) / 256, 256, 0, stream>>>(
        row_ptr, blocksums, cursor, np1, n_nodes);
    csr_fill_kernel<<<(n_edges + 255) / 256, 256, 0, stream>>>(
        src, dst, cursor, esrc, n_edges);

    const int agg_grid = (n_nodes + 3) / 4;
    const int ngroups = (n_nodes + 15) / 16;
    const int lin_grid = (ngroups + 7) / 8;   // 4 waves/block, ~2 groups/wave

    // ---- layer 1 ----
    agg_kernel<<<agg_grid, 256, 0, stream>>>(
        (const float2*)bufA, row_ptr, esrc, (float2*)bufB, n_nodes);
    linear_mfma_kernel<<<lin_grid, 256, 0, stream>>>(
        bufB, W1hi, W1lo, b1, bufA, nullptr, nullptr, nullptr, n_nodes, 0);

    // ---- layer 2 + fused output head ----
    agg_kernel<<<agg_grid, 256, 0, stream>>>(
        (const float2*)bufA, row_ptr, esrc, (float2*)bufB, n_nodes);
    linear_mfma_kernel<<<lin_grid, 256, 0, stream>>>(
        bufB, W2hi, W2lo, b2, nullptr, Wout, bout, out, n_nodes, 1);
}

// Round 4
// 751.286 us; speedup vs baseline: 8.4555x; 1.1584x over previous
//
#include <hip/hip_runtime.h>
#include <math.h>

#define D 128
#define SCAN_B 256   // elements per scan block

typedef __attribute__((ext_vector_type(8))) short bfrag;   // 8 bf16 (4 VGPRs)
typedef __attribute__((ext_vector_type(4))) float ffrag;   // 4 fp32 acc

__device__ inline unsigned short f2bf(float f) {           // RNE fp32->bf16
    unsigned u = __float_as_uint(f);
    u += 0x7FFF + ((u >> 16) & 1);
    return (unsigned short)(u >> 16);
}
__device__ inline float bf2f(unsigned short h) {
    return __uint_as_float(((unsigned)h) << 16);
}
__device__ inline unsigned pack_bf2(float a, float b) {    // [lo=a, hi=b]
    return ((unsigned)f2bf(a)) | (((unsigned)f2bf(b)) << 16);
}

// ---------------- zero int buffer ----------------
__global__ void zero_int_kernel(int* __restrict__ buf, int n) {
    int i = blockIdx.x * blockDim.x + threadIdx.x;
    if (i < n) buf[i] = 0;
}

// ---------------- split W (fp32) -> Whi + Wlo (bf16) ----------------
__global__ void wsplit_kernel(const float* __restrict__ W,
                              unsigned short* __restrict__ hi,
                              unsigned short* __restrict__ lo, int n) {
    int i = blockIdx.x * blockDim.x + threadIdx.x;
    if (i >= n) return;
    float f = W[i];
    unsigned short h = f2bf(f);
    hi[i] = h;
    lo[i] = f2bf(f - bf2f(h));
}

// ---------------- h0 = bf16(emb_table[cncpt_ids]) ----------------
// one thread = 4 dims (float4 read -> uint2 bf16 write); 32 threads/row
__global__ void gather_kernel(const float* __restrict__ emb,
                              const int* __restrict__ ids,
                              unsigned* __restrict__ h, int n_nodes) {
    int idx = blockIdx.x * blockDim.x + threadIdx.x;
    int total = n_nodes * 32;
    if (idx >= total) return;
    int node = idx >> 5;
    int c = idx & 31;
    size_t cid = (size_t)ids[node];
    float4 v = ((const float4*)(emb + cid * D))[c];
    uint2 p;
    p.x = pack_bf2(v.x, v.y);
    p.y = pack_bf2(v.z, v.w);
    ((uint2*)(h + (size_t)node * 64))[c] = p;
}

// ---------------- CSR build ----------------
__global__ void degree_kernel(const int* __restrict__ dst,
                              int* __restrict__ deg, int n_edges) {
    int e = blockIdx.x * blockDim.x + threadIdx.x;
    if (e < n_edges) atomicAdd(&deg[dst[e]], 1);
}

__global__ __launch_bounds__(SCAN_B) void scan_block_kernel(
        const int* __restrict__ deg, int* __restrict__ row_ptr,
        int* __restrict__ blocksums, int n) {
    __shared__ int s[SCAN_B];
    int i = blockIdx.x * SCAN_B + threadIdx.x;
    int v = (i < n) ? deg[i] : 0;
    s[threadIdx.x] = v;
    __syncthreads();
    #pragma unroll
    for (int off = 1; off < SCAN_B; off <<= 1) {
        int t = (threadIdx.x >= off) ? s[threadIdx.x - off] : 0;
        __syncthreads();
        s[threadIdx.x] += t;
        __syncthreads();
    }
    if (i < n) row_ptr[i] = s[threadIdx.x] - v;      // exclusive
    if (threadIdx.x == SCAN_B - 1) blocksums[blockIdx.x] = s[SCAN_B - 1];
}

__global__ __launch_bounds__(512) void scan_sums_kernel(int* __restrict__ blocksums,
                                                        int nb) {
    __shared__ int s[512];
    int v = (threadIdx.x < nb) ? blocksums[threadIdx.x] : 0;
    s[threadIdx.x] = v;
    __syncthreads();
    #pragma unroll
    for (int off = 1; off < 512; off <<= 1) {
        int t = (threadIdx.x >= off) ? s[threadIdx.x - off] : 0;
        __syncthreads();
        s[threadIdx.x] += t;
        __syncthreads();
    }
    if (threadIdx.x < nb) blocksums[threadIdx.x] = s[threadIdx.x] - v;  // exclusive
}

__global__ void add_offsets_kernel(int* __restrict__ row_ptr,
                                   const int* __restrict__ blocksums,
                                   int* __restrict__ cursor, int n, int n_nodes) {
    int i = blockIdx.x * blockDim.x + threadIdx.x;
    if (i >= n) return;
    int rp = row_ptr[i] + blocksums[i / SCAN_B];
    row_ptr[i] = rp;
    if (i < n_nodes) cursor[i] = rp;
}

__global__ void csr_fill_kernel(const int* __restrict__ src,
                                const int* __restrict__ dst,
                                int* __restrict__ cursor,
                                int* __restrict__ esrc, int n_edges) {
    int e = blockIdx.x * blockDim.x + threadIdx.x;
    if (e >= n_edges) return;
    int pos = atomicAdd(&cursor[dst[e]], 1);
    esrc[pos] = src[e];
}

// ---------------- agg[v] = sum_{e: dst=v} h[src[e]]  (bf16 in/out) ----------------
// One wave per node; lane owns 2 dims (one packed uint). fp32 accumulate.
__global__ __launch_bounds__(256) void agg_kernel(
        const unsigned* __restrict__ h, const int* __restrict__ row_ptr,
        const int* __restrict__ esrc, unsigned* __restrict__ agg, int n_nodes) {
    int node = blockIdx.x * 4 + (threadIdx.x >> 6);
    int lane = threadIdx.x & 63;
    if (node >= n_nodes) return;
    int beg = row_ptr[node], end = row_ptr[node + 1];
    float ax = 0.f, ay = 0.f;
    int i = beg;
    for (; i + 3 < end; i += 4) {
        unsigned u0 = h[(size_t)esrc[i]     * 64 + lane];
        unsigned u1 = h[(size_t)esrc[i + 1] * 64 + lane];
        unsigned u2 = h[(size_t)esrc[i + 2] * 64 + lane];
        unsigned u3 = h[(size_t)esrc[i + 3] * 64 + lane];
        ax += __uint_as_float(u0 << 16) + __uint_as_float(u1 << 16)
            + __uint_as_float(u2 << 16) + __uint_as_float(u3 << 16);
        ay += __uint_as_float(u0 & 0xffff0000u) + __uint_as_float(u1 & 0xffff0000u)
            + __uint_as_float(u2 & 0xffff0000u) + __uint_as_float(u3 & 0xffff0000u);
    }
    for (; i < end; ++i) {
        unsigned u = h[(size_t)esrc[i] * 64 + lane];
        ax += __uint_as_float(u << 16);
        ay += __uint_as_float(u & 0xffff0000u);
    }
    agg[(size_t)node * 64 + lane] = pack_bf2(ax, ay);
}

// ---------------- y = relu(x @ W^T + b) via bf16 MFMA (x exact bf16) ----------------
// One wave per 16-node group; all 128 output dims (8 nt-tiles of 16).
// A-frag: direct 16B load of x[node][kt*32+quad*8 .. +7] (bf16 row-major).
// B-frag: W[n][k..k+7] from pre-split Whi/Wlo. C = A*Whi + A*Wlo (2 MFMAs).
// fuse_out: relu+bias, dot with wout, quad shfl-reduce, sigmoid -> logits.
__global__ __launch_bounds__(256) void linear_mfma_kernel(
        const unsigned short* __restrict__ x,
        const unsigned short* __restrict__ Whi,
        const unsigned short* __restrict__ Wlo,
        const float* __restrict__ b,
        unsigned short* __restrict__ y,
        const float* __restrict__ wout,
        const float* __restrict__ bout,
        float* __restrict__ outp,
        int n_nodes, int fuse_out) {
    const int lane = threadIdx.x & 63;
    const int col  = lane & 15;        // m (A) / n (B) index
    const int quad = lane >> 4;        // k-chunk selector
    const int wave = blockIdx.x * 4 + (threadIdx.x >> 6);
    const int nwaves = gridDim.x * 4;
    const int ngroups = (n_nodes + 15) >> 4;

    float bvals[8], wvals[8];
    #pragma unroll
    for (int nt = 0; nt < 8; ++nt) {
        bvals[nt] = b[nt * 16 + col];
        wvals[nt] = fuse_out ? wout[nt * 16 + col] : 0.f;
    }
    const float bout0 = fuse_out ? bout[0] : 0.f;

    for (int g = wave; g < ngroups; g += nwaves) {
        int node = g * 16 + col;
        int nload = node < n_nodes ? node : (n_nodes - 1);

        // ---- direct bf16 A fragments (4 kt chunks of 8) ----
        bfrag a[4];
        #pragma unroll
        for (int kt = 0; kt < 4; ++kt)
            a[kt] = *(const bfrag*)(x + (size_t)nload * D + kt * 32 + quad * 8);

        const size_t bbase = (size_t)col * D + quad * 8;   // within-row offset
        float part0 = 0.f, part1 = 0.f, part2 = 0.f, part3 = 0.f;

        #pragma unroll
        for (int nt = 0; nt < 8; ++nt) {
            ffrag c = {0.f, 0.f, 0.f, 0.f};
            #pragma unroll
            for (int kt = 0; kt < 4; ++kt) {
                size_t off = (size_t)nt * 16 * D + bbase + kt * 32;
                bfrag bh = *(const bfrag*)(Whi + off);
                bfrag bl = *(const bfrag*)(Wlo + off);
                c = __builtin_amdgcn_mfma_f32_16x16x32_bf16(a[kt], bh, c, 0, 0, 0);
                c = __builtin_amdgcn_mfma_f32_16x16x32_bf16(a[kt], bl, c, 0, 0, 0);
            }
            // C layout: value r is C[row = quad*4 + r][col]
            if (fuse_out) {
                part0 += fmaxf(c[0] + bvals[nt], 0.f) * wvals[nt];
                part1 += fmaxf(c[1] + bvals[nt], 0.f) * wvals[nt];
                part2 += fmaxf(c[2] + bvals[nt], 0.f) * wvals[nt];
                part3 += fmaxf(c[3] + bvals[nt], 0.f) * wvals[nt];
            } else {
                #pragma unroll
                for (int r = 0; r < 4; ++r) {
                    int onode = g * 16 + quad * 4 + r;
                    if (onode < n_nodes)
                        y[(size_t)onode * D + nt * 16 + col] =
                            f2bf(fmaxf(c[r] + bvals[nt], 0.f));
                }
            }
        }

        if (fuse_out) {
            float part[4] = {part0, part1, part2, part3};
            #pragma unroll
            for (int r = 0; r < 4; ++r) {
                float s = part[r];
                s += __shfl_xor(s, 1, 64);
                s += __shfl_xor(s, 2, 64);
                s += __shfl_xor(s, 4, 64);
                s += __shfl_xor(s, 8, 64);   // reduce over 16 cols within quad
                int onode = g * 16 + quad * 4 + r;
                if (col == 0 && onode < n_nodes)
                    outp[onode] = 1.0f / (1.0f + expf(-(s + bout0)));
            }
        }
    }
}

extern "C" void kernel_launch(void* const* d_in, const int* in_sizes, int n_in,
                              void* d_out, int out_size, void* d_ws, size_t ws_size,
                              hipStream_t stream) {
    const int*   cncpt_ids = (const int*)d_in[0];
    const int*   src       = (const int*)d_in[1];
    const int*   dst       = (const int*)d_in[2];
    const float* emb       = (const float*)d_in[3];
    const float* W1        = (const float*)d_in[4];
    const float* b1        = (const float*)d_in[5];
    const float* W2        = (const float*)d_in[6];
    const float* b2        = (const float*)d_in[7];
    const float* Wout      = (const float*)d_in[8];
    const float* bout      = (const float*)d_in[9];
    float* out = (float*)d_out;

    const int n_nodes = in_sizes[0];
    const int n_edges = in_sizes[1];

    // ---- workspace carve-up ----
    unsigned short* bufA = (unsigned short*)d_ws;          // N*D bf16
    unsigned short* bufB = bufA + (size_t)n_nodes * D;     // N*D bf16
    int*   deg      = (int*)(bufB + (size_t)n_nodes * D);  // N+1 ints
    int*   row_ptr  = deg + (n_nodes + 1);                 // N+1 ints
    int*   cursor   = row_ptr + (n_nodes + 1);             // N ints
    int*   blocksums= cursor + n_nodes;                    // 512 ints
    int*   esrc     = blocksums + 512;                     // E ints
    unsigned short* W1hi = (unsigned short*)(esrc + n_edges);  // D*D each
    unsigned short* W1lo = W1hi + D * D;
    unsigned short* W2hi = W1lo + D * D;
    unsigned short* W2lo = W2hi + D * D;

    const int np1 = n_nodes + 1;
    const int nb_scan = (np1 + SCAN_B - 1) / SCAN_B;  // <= 512

    // ---- weight splits (bf16 hi/lo) ----
    wsplit_kernel<<<(D * D + 255) / 256, 256, 0, stream>>>(W1, W1hi, W1lo, D * D);
    wsplit_kernel<<<(D * D + 255) / 256, 256, 0, stream>>>(W2, W2hi, W2lo, D * D);

    // ---- h0 = bf16(emb[ids]) -> bufA ----
    gather_kernel<<<(n_nodes * 32 + 255) / 256, 256, 0, stream>>>(
        emb, cncpt_ids, (unsigned*)bufA, n_nodes);

    // ---- CSR build (per call; ws is re-poisoned) ----
    zero_int_kernel<<<(np1 + 255) / 256, 256, 0, stream>>>(deg, np1);
    degree_kernel<<<(n_edges + 255) / 256, 256, 0, stream>>>(dst, deg, n_edges);
    scan_block_kernel<<<nb_scan, SCAN_B, 0, stream>>>(deg, row_ptr, blocksums, np1);
    scan_sums_kernel<<<1, 512, 0, stream>>>(blocksums, nb_scan);
    add_offsets_kernel<<<(np1 + 255) / 256, 256, 0, stream>>>(
        row_ptr, blocksums, cursor, np1, n_nodes);
    csr_fill_kernel<<<(n_edges + 255) / 256, 256, 0, stream>>>(
        src, dst, cursor, esrc, n_edges);

    const int agg_grid = (n_nodes + 3) / 4;
    const int ngroups = (n_nodes + 15) / 16;
    const int lin_grid = (ngroups + 7) / 8;   // 4 waves/block, ~2 groups/wave

    // ---- layer 1 ----
    agg_kernel<<<agg_grid, 256, 0, stream>>>(
        (const unsigned*)bufA, row_ptr, esrc, (unsigned*)bufB, n_nodes);
    linear_mfma_kernel<<<lin_grid, 256, 0, stream>>>(
        bufB, W1hi, W1lo, b1, bufA, nullptr, nullptr, nullptr, n_nodes, 0);

    // ---- layer 2 + fused output head ----
    agg_kernel<<<agg_grid, 256, 0, stream>>>(
        (const unsigned*)bufA, row_ptr, esrc, (unsigned*)bufB, n_nodes);
    linear_mfma_kernel<<<lin_grid, 256, 0, stream>>>(
        bufB, W2hi, W2lo, b2, nullptr, Wout, bout, out, n_nodes, 1);
}

// Round 5
// 725.537 us; speedup vs baseline: 8.7556x; 1.0355x over previous
//
#include <hip/hip_runtime.h>
#include <math.h>

#define D 128
#define SCAN_B 256   // elements per scan block

typedef __attribute__((ext_vector_type(8))) short bfrag;   // 8 bf16 (4 VGPRs)
typedef __attribute__((ext_vector_type(4))) float ffrag;   // 4 fp32 acc

__device__ inline unsigned short f2bf(float f) {           // RNE fp32->bf16
    unsigned u = __float_as_uint(f);
    u += 0x7FFF + ((u >> 16) & 1);
    return (unsigned short)(u >> 16);
}
__device__ inline float bf2f(unsigned short h) {
    return __uint_as_float(((unsigned)h) << 16);
}
__device__ inline unsigned pack_bf2(float a, float b) {    // [lo=a, hi=b]
    return ((unsigned)f2bf(a)) | (((unsigned)f2bf(b)) << 16);
}

// ---------------- zero int buffer ----------------
__global__ void zero_int_kernel(int* __restrict__ buf, int n) {
    int i = blockIdx.x * blockDim.x + threadIdx.x;
    if (i < n) buf[i] = 0;
}

// ---------------- split W1,W2 (fp32) -> bf16 hi/lo (one launch) ----------------
__global__ void wsplit_kernel(const float* __restrict__ W1,
                              const float* __restrict__ W2,
                              unsigned short* __restrict__ hi1,
                              unsigned short* __restrict__ lo1,
                              unsigned short* __restrict__ hi2,
                              unsigned short* __restrict__ lo2, int n) {
    int i = blockIdx.x * blockDim.x + threadIdx.x;
    if (i >= n) return;
    float f1 = W1[i];
    unsigned short h1 = f2bf(f1);
    hi1[i] = h1;
    lo1[i] = f2bf(f1 - bf2f(h1));
    float f2 = W2[i];
    unsigned short h2 = f2bf(f2);
    hi2[i] = h2;
    lo2[i] = f2bf(f2 - bf2f(h2));
}

// ---------------- h0 = bf16(emb_table[cncpt_ids]) ----------------
// one thread = 8 dims (two float4 reads -> one uint4 bf16 write); 16 thr/row
__global__ void gather_kernel(const float* __restrict__ emb,
                              const int* __restrict__ ids,
                              uint4* __restrict__ h4, int n_nodes) {
    int idx = blockIdx.x * blockDim.x + threadIdx.x;
    int total = n_nodes * 16;
    if (idx >= total) return;
    int node = idx >> 4;
    int c = idx & 15;
    size_t cid = (size_t)ids[node];
    const float4* s = (const float4*)(emb + cid * D) + c * 2;
    float4 v0 = s[0];
    float4 v1 = s[1];
    uint4 p;
    p.x = pack_bf2(v0.x, v0.y);
    p.y = pack_bf2(v0.z, v0.w);
    p.z = pack_bf2(v1.x, v1.y);
    p.w = pack_bf2(v1.z, v1.w);
    h4[(size_t)node * 16 + c] = p;
}

// ---------------- CSR build ----------------
__global__ void degree_kernel(const int* __restrict__ dst,
                              int* __restrict__ deg, int n_edges) {
    int e = blockIdx.x * blockDim.x + threadIdx.x;
    if (e < n_edges) atomicAdd(&deg[dst[e]], 1);
}

__global__ __launch_bounds__(SCAN_B) void scan_block_kernel(
        const int* __restrict__ deg, int* __restrict__ row_ptr,
        int* __restrict__ blocksums, int n) {
    __shared__ int s[SCAN_B];
    int i = blockIdx.x * SCAN_B + threadIdx.x;
    int v = (i < n) ? deg[i] : 0;
    s[threadIdx.x] = v;
    __syncthreads();
    #pragma unroll
    for (int off = 1; off < SCAN_B; off <<= 1) {
        int t = (threadIdx.x >= off) ? s[threadIdx.x - off] : 0;
        __syncthreads();
        s[threadIdx.x] += t;
        __syncthreads();
    }
    if (i < n) row_ptr[i] = s[threadIdx.x] - v;      // exclusive
    if (threadIdx.x == SCAN_B - 1) blocksums[blockIdx.x] = s[SCAN_B - 1];
}

__global__ __launch_bounds__(512) void scan_sums_kernel(int* __restrict__ blocksums,
                                                        int nb) {
    __shared__ int s[512];
    int v = (threadIdx.x < nb) ? blocksums[threadIdx.x] : 0;
    s[threadIdx.x] = v;
    __syncthreads();
    #pragma unroll
    for (int off = 1; off < 512; off <<= 1) {
        int t = (threadIdx.x >= off) ? s[threadIdx.x - off] : 0;
        __syncthreads();
        s[threadIdx.x] += t;
        __syncthreads();
    }
    if (threadIdx.x < nb) blocksums[threadIdx.x] = s[threadIdx.x] - v;  // exclusive
}

__global__ void add_offsets_kernel(int* __restrict__ row_ptr,
                                   const int* __restrict__ blocksums,
                                   int* __restrict__ cursor, int n, int n_nodes) {
    int i = blockIdx.x * blockDim.x + threadIdx.x;
    if (i >= n) return;
    int rp = row_ptr[i] + blocksums[i / SCAN_B];
    row_ptr[i] = rp;
    if (i < n_nodes) cursor[i] = rp;
}

__global__ void csr_fill_kernel(const int* __restrict__ src,
                                const int* __restrict__ dst,
                                int* __restrict__ cursor,
                                int* __restrict__ esrc, int n_edges) {
    int e = blockIdx.x * blockDim.x + threadIdx.x;
    if (e >= n_edges) return;
    int pos = atomicAdd(&cursor[dst[e]], 1);
    esrc[pos] = src[e];
}

// ---------------- agg[v] = sum_{e: dst=v} h[src[e]]  (bf16 in/out) ----------------
// One wave per node. 16 lanes cover a 256B row with uint4 (16B) loads; lane
// group g = lane>>4 strides the edge list by 4 -> one wave-load = 4 edges.
// Unroll x2: two independent 1KB gathers in flight. fp32 accumulate,
// cross-group shfl_xor combine, packed bf16 uint4 write.
__global__ __launch_bounds__(256) void agg_kernel(
        const uint4* __restrict__ h4, const int* __restrict__ row_ptr,
        const int* __restrict__ esrc, uint4* __restrict__ agg4, int n_nodes) {
    int node = blockIdx.x * 4 + (threadIdx.x >> 6);
    int lane = threadIdx.x & 63;
    if (node >= n_nodes) return;
    const int c = lane & 15;     // uint4 chunk within row (dims c*8 .. c*8+7)
    const int g = lane >> 4;     // edge group 0..3
    int beg = row_ptr[node], end = row_ptr[node + 1];

    float a0 = 0.f, a1 = 0.f, a2 = 0.f, a3 = 0.f;
    float a4 = 0.f, a5 = 0.f, a6 = 0.f, a7 = 0.f;

    int i = beg + g;             // this lane-group's edges: beg+g, +4, +8, ...
    for (; i + 4 < end; i += 8) {
        int s0 = esrc[i];
        int s1 = esrc[i + 4];
        uint4 u0 = h4[(size_t)s0 * 16 + c];
        uint4 u1 = h4[(size_t)s1 * 16 + c];
        a0 += __uint_as_float(u0.x << 16) + __uint_as_float(u1.x << 16);
        a1 += __uint_as_float(u0.x & 0xffff0000u) + __uint_as_float(u1.x & 0xffff0000u);
        a2 += __uint_as_float(u0.y << 16) + __uint_as_float(u1.y << 16);
        a3 += __uint_as_float(u0.y & 0xffff0000u) + __uint_as_float(u1.y & 0xffff0000u);
        a4 += __uint_as_float(u0.z << 16) + __uint_as_float(u1.z << 16);
        a5 += __uint_as_float(u0.z & 0xffff0000u) + __uint_as_float(u1.z & 0xffff0000u);
        a6 += __uint_as_float(u0.w << 16) + __uint_as_float(u1.w << 16);
        a7 += __uint_as_float(u0.w & 0xffff0000u) + __uint_as_float(u1.w & 0xffff0000u);
    }
    if (i < end) {
        uint4 u = h4[(size_t)esrc[i] * 16 + c];
        a0 += __uint_as_float(u.x << 16);
        a1 += __uint_as_float(u.x & 0xffff0000u);
        a2 += __uint_as_float(u.y << 16);
        a3 += __uint_as_float(u.y & 0xffff0000u);
        a4 += __uint_as_float(u.z << 16);
        a5 += __uint_as_float(u.z & 0xffff0000u);
        a6 += __uint_as_float(u.w << 16);
        a7 += __uint_as_float(u.w & 0xffff0000u);
    }

    // combine the 4 lane groups (lanes c, c+16, c+32, c+48 hold same dims)
    a0 += __shfl_xor(a0, 16, 64); a0 += __shfl_xor(a0, 32, 64);
    a1 += __shfl_xor(a1, 16, 64); a1 += __shfl_xor(a1, 32, 64);
    a2 += __shfl_xor(a2, 16, 64); a2 += __shfl_xor(a2, 32, 64);
    a3 += __shfl_xor(a3, 16, 64); a3 += __shfl_xor(a3, 32, 64);
    a4 += __shfl_xor(a4, 16, 64); a4 += __shfl_xor(a4, 32, 64);
    a5 += __shfl_xor(a5, 16, 64); a5 += __shfl_xor(a5, 32, 64);
    a6 += __shfl_xor(a6, 16, 64); a6 += __shfl_xor(a6, 32, 64);
    a7 += __shfl_xor(a7, 16, 64); a7 += __shfl_xor(a7, 32, 64);

    if (g == 0) {
        uint4 r;
        r.x = pack_bf2(a0, a1);
        r.y = pack_bf2(a2, a3);
        r.z = pack_bf2(a4, a5);
        r.w = pack_bf2(a6, a7);
        agg4[(size_t)node * 16 + c] = r;
    }
}

// ---------------- y = relu(x @ W^T + b) via bf16 MFMA (x exact bf16) ----------------
__global__ __launch_bounds__(256) void linear_mfma_kernel(
        const unsigned short* __restrict__ x,
        const unsigned short* __restrict__ Whi,
        const unsigned short* __restrict__ Wlo,
        const float* __restrict__ b,
        unsigned short* __restrict__ y,
        const float* __restrict__ wout,
        const float* __restrict__ bout,
        float* __restrict__ outp,
        int n_nodes, int fuse_out) {
    const int lane = threadIdx.x & 63;
    const int col  = lane & 15;        // m (A) / n (B) index
    const int quad = lane >> 4;        // k-chunk selector
    const int wave = blockIdx.x * 4 + (threadIdx.x >> 6);
    const int nwaves = gridDim.x * 4;
    const int ngroups = (n_nodes + 15) >> 4;

    float bvals[8], wvals[8];
    #pragma unroll
    for (int nt = 0; nt < 8; ++nt) {
        bvals[nt] = b[nt * 16 + col];
        wvals[nt] = fuse_out ? wout[nt * 16 + col] : 0.f;
    }
    const float bout0 = fuse_out ? bout[0] : 0.f;

    for (int g = wave; g < ngroups; g += nwaves) {
        int node = g * 16 + col;
        int nload = node < n_nodes ? node : (n_nodes - 1);

        bfrag a[4];
        #pragma unroll
        for (int kt = 0; kt < 4; ++kt)
            a[kt] = *(const bfrag*)(x + (size_t)nload * D + kt * 32 + quad * 8);

        const size_t bbase = (size_t)col * D + quad * 8;   // within-row offset
        float part0 = 0.f, part1 = 0.f, part2 = 0.f, part3 = 0.f;

        #pragma unroll
        for (int nt = 0; nt < 8; ++nt) {
            ffrag c = {0.f, 0.f, 0.f, 0.f};
            #pragma unroll
            for (int kt = 0; kt < 4; ++kt) {
                size_t off = (size_t)nt * 16 * D + bbase + kt * 32;
                bfrag bh = *(const bfrag*)(Whi + off);
                bfrag bl = *(const bfrag*)(Wlo + off);
                c = __builtin_amdgcn_mfma_f32_16x16x32_bf16(a[kt], bh, c, 0, 0, 0);
                c = __builtin_amdgcn_mfma_f32_16x16x32_bf16(a[kt], bl, c, 0, 0, 0);
            }
            // C layout: value r is C[row = quad*4 + r][col]
            if (fuse_out) {
                part0 += fmaxf(c[0] + bvals[nt], 0.f) * wvals[nt];
                part1 += fmaxf(c[1] + bvals[nt], 0.f) * wvals[nt];
                part2 += fmaxf(c[2] + bvals[nt], 0.f) * wvals[nt];
                part3 += fmaxf(c[3] + bvals[nt], 0.f) * wvals[nt];
            } else {
                #pragma unroll
                for (int r = 0; r < 4; ++r) {
                    int onode = g * 16 + quad * 4 + r;
                    if (onode < n_nodes)
                        y[(size_t)onode * D + nt * 16 + col] =
                            f2bf(fmaxf(c[r] + bvals[nt], 0.f));
                }
            }
        }

        if (fuse_out) {
            float part[4] = {part0, part1, part2, part3};
            #pragma unroll
            for (int r = 0; r < 4; ++r) {
                float s = part[r];
                s += __shfl_xor(s, 1, 64);
                s += __shfl_xor(s, 2, 64);
                s += __shfl_xor(s, 4, 64);
                s += __shfl_xor(s, 8, 64);   // reduce over 16 cols within quad
                int onode = g * 16 + quad * 4 + r;
                if (col == 0 && onode < n_nodes)
                    outp[onode] = 1.0f / (1.0f + expf(-(s + bout0)));
            }
        }
    }
}

extern "C" void kernel_launch(void* const* d_in, const int* in_sizes, int n_in,
                              void* d_out, int out_size, void* d_ws, size_t ws_size,
                              hipStream_t stream) {
    const int*   cncpt_ids = (const int*)d_in[0];
    const int*   src       = (const int*)d_in[1];
    const int*   dst       = (const int*)d_in[2];
    const float* emb       = (const float*)d_in[3];
    const float* W1        = (const float*)d_in[4];
    const float* b1        = (const float*)d_in[5];
    const float* W2        = (const float*)d_in[6];
    const float* b2        = (const float*)d_in[7];
    const float* Wout      = (const float*)d_in[8];
    const float* bout      = (const float*)d_in[9];
    float* out = (float*)d_out;

    const int n_nodes = in_sizes[0];
    const int n_edges = in_sizes[1];

    // ---- workspace carve-up ----
    unsigned short* bufA = (unsigned short*)d_ws;          // N*D bf16
    unsigned short* bufB = bufA + (size_t)n_nodes * D;     // N*D bf16
    int*   deg      = (int*)(bufB + (size_t)n_nodes * D);  // N+1 ints
    int*   row_ptr  = deg + (n_nodes + 1);                 // N+1 ints
    int*   cursor   = row_ptr + (n_nodes + 1);             // N ints
    int*   blocksums= cursor + n_nodes;                    // 512 ints
    int*   esrc     = blocksums + 512;                     // E ints
    unsigned short* W1hi = (unsigned short*)(esrc + n_edges);  // D*D each
    unsigned short* W1lo = W1hi + D * D;
    unsigned short* W2hi = W1lo + D * D;
    unsigned short* W2lo = W2hi + D * D;

    const int np1 = n_nodes + 1;
    const int nb_scan = (np1 + SCAN_B - 1) / SCAN_B;  // <= 512

    // ---- weight splits (bf16 hi/lo) ----
    wsplit_kernel<<<(D * D + 255) / 256, 256, 0, stream>>>(
        W1, W2, W1hi, W1lo, W2hi, W2lo, D * D);

    // ---- h0 = bf16(emb[ids]) -> bufA ----
    gather_kernel<<<(n_nodes * 16 + 255) / 256, 256, 0, stream>>>(
        emb, cncpt_ids, (uint4*)bufA, n_nodes);

    // ---- CSR build (per call; ws is re-poisoned) ----
    zero_int_kernel<<<(np1 + 255) / 256, 256, 0, stream>>>(deg, np1);
    degree_kernel<<<(n_edges + 255) / 256, 256, 0, stream>>>(dst, deg, n_edges);
    scan_block_kernel<<<nb_scan, SCAN_B, 0, stream>>>(deg, row_ptr, blocksums, np1);
    scan_sums_kernel<<<1, 512, 0, stream>>>(blocksums, nb_scan);
    add_offsets_kernel<<<(np1 + 255) / 256, 256, 0, stream>>>(
        row_ptr, blocksums, cursor, np1, n_nodes);
    csr_fill_kernel<<<(n_edges + 255) / 256, 256, 0, stream>>>(
        src, dst, cursor, esrc, n_edges);

    const int agg_grid = (n_nodes + 3) / 4;
    const int ngroups = (n_nodes + 15) / 16;
    const int lin_grid = (ngroups + 7) / 8;   // 4 waves/block, ~2 groups/wave

    // ---- layer 1 ----
    agg_kernel<<<agg_grid, 256, 0, stream>>>(
        (const uint4*)bufA, row_ptr, esrc, (uint4*)bufB, n_nodes);
    linear_mfma_kernel<<<lin_grid, 256, 0, stream>>>(
        bufB, W1hi, W1lo, b1, bufA, nullptr, nullptr, nullptr, n_nodes, 0);

    // ---- layer 2 + fused output head ----
    agg_kernel<<<agg_grid, 256, 0, stream>>>(
        (const uint4*)bufA, row_ptr, esrc, (uint4*)bufB, n_nodes);
    linear_mfma_kernel<<<lin_grid, 256, 0, stream>>>(
        bufB, W2hi, W2lo, b2, nullptr, Wout, bout, out, n_nodes, 1);
}